// Round 5
// baseline (184.563 us; speedup 1.0000x reference)
//
#include <hip/hip_runtime.h>
#include <math.h>

#define B_  32
#define NS_ 50
#define NQ_ 75
#define T_  128
#define F_  64
#define D_  256
#define K_  5
#define NR_ (NS_ + NQ_)   // 125 items per episode (supports then queries)
#define QT_ 5             // query tile per stage-2 block (75 = 15 * 5)
#define NTILE_ 15
#define ISTRIDE_ 128      // meanbuf floats per item (2 partial rows of 64)

typedef float v4f __attribute__((ext_vector_type(4)));

// ---------------------------------------------------------------------------
// Stage 1: time-mean pool, TWO WAVES PER ITEM (each sums 64 of 128 t-rows).
// No barriers, no LDS. 8000 waves (~31/CU — full wave-slot occupancy),
// per-wave: 16 float4 loads (each instr = 1 KB contiguous wave read), 4
// independent accumulators, 2 shuffle rounds, lanes 0-15 store the scaled
// partial row. Stage 2 adds the two halves (meanbuf is tiny & L2-hot).
// ---------------------------------------------------------------------------
__global__ __launch_bounds__(256) void meanpool_kernel(
    const float* __restrict__ sx, const float* __restrict__ qx,
    float* __restrict__ meanbuf)
{
    const int wid  = (blockIdx.x << 2) + (threadIdx.x >> 6);  // 0 .. 7999
    const int lane = threadIdx.x & 63;
    const int item = wid >> 1, half = wid & 1;
    const int b = item / NR_, n = item % NR_;
    const float* src = (n < NS_)
        ? (sx + (size_t)(b * NS_ + n) * (T_ * F_))
        : (qx + (size_t)(b * NQ_ + (n - NS_)) * (T_ * F_));
    const v4f* src4 = (const v4f*)src + half * 1024;   // 64 t-rows = 1024 float4

    v4f a0 = 0.f, a1 = 0.f, a2 = 0.f, a3 = 0.f;
#pragma unroll
    for (int s = 0; s < 16; s += 4) {
        v4f v0 = src4[(s + 0) * 64 + lane];
        v4f v1 = src4[(s + 1) * 64 + lane];
        v4f v2 = src4[(s + 2) * 64 + lane];
        v4f v3 = src4[(s + 3) * 64 + lane];
        a0 += v0; a1 += v1; a2 += v2; a3 += v3;
    }
    v4f a = (a0 + a1) + (a2 + a3);

    // lanes {l, l+16, l+32, l+48} hold partials of the same f4-column
    a.x += __shfl_down(a.x, 32); a.y += __shfl_down(a.y, 32);
    a.z += __shfl_down(a.z, 32); a.w += __shfl_down(a.w, 32);
    a.x += __shfl_down(a.x, 16); a.y += __shfl_down(a.y, 16);
    a.z += __shfl_down(a.z, 16); a.w += __shfl_down(a.w, 16);

    if (lane < 16)
        ((v4f*)meanbuf)[(size_t)item * 32 + half * 16 + lane] = a * (1.f / T_);
}

// ---------------------------------------------------------------------------
// Stage 2: one block per (episode, query-tile of 5). 480 blocks, 256 threads.
//  A) label-grouped protomeans from support partial-means (adds both halves)
//  B) project 10 rows (5 query means + 5 protomeans) through W:
//     thread d caches W[:,d]; rows broadcast from LDS as float2.
//  C) 25 (q,k) pairs over 4 waves: shuffle-reduce Sum((qz-pz)^2) over D=256.
// ---------------------------------------------------------------------------
__global__ __launch_bounds__(256) void proto_kernel(
    const float* __restrict__ meanbuf, const int* __restrict__ sy,
    const float* __restrict__ Wm, const float* __restrict__ bias,
    float* __restrict__ out)
{
    __shared__ float rows[QT_ + K_][F_];   // [0..4] query means, [5..9] protomeans
    __shared__ float zbuf[QT_ + K_][D_];   // projected rows
    __shared__ int   labels[NS_];
    __shared__ float psum[K_][F_];
    __shared__ int   counts[K_];

    const int tid = threadIdx.x;
    const int bid = blockIdx.x;            // 0 .. B*NTILE-1
    const int b = bid / NTILE_, qt = bid % NTILE_;
    const int q0 = qt * QT_;

    if (tid < NS_) labels[tid] = sy[b * NS_ + tid];
    __syncthreads();

    // A) class sums over support means (threads 0..63, f = tid)
    if (tid < F_) {
        const int f = tid;
        float p0 = 0.f, p1 = 0.f, p2 = 0.f, p3 = 0.f, p4 = 0.f;
        for (int s = 0; s < NS_; ++s) {
            const float* mrow = meanbuf + (size_t)(b * NR_ + s) * ISTRIDE_;
            float v = mrow[f] + mrow[F_ + f];          // combine the two halves
            int l = labels[s];
            if      (l == 0) p0 += v;
            else if (l == 1) p1 += v;
            else if (l == 2) p2 += v;
            else if (l == 3) p3 += v;
            else             p4 += v;
        }
        psum[0][f] = p0; psum[1][f] = p1; psum[2][f] = p2;
        psum[3][f] = p3; psum[4][f] = p4;
    }
    if (tid < K_) {
        int c = 0;
        for (int s = 0; s < NS_; ++s) c += (labels[s] == tid);
        counts[tid] = c;
    }
    for (int i = tid; i < QT_ * F_; i += 256) {
        int r = i / F_, f = i % F_;
        const float* mrow = meanbuf + (size_t)(b * NR_ + NS_ + q0 + r) * ISTRIDE_;
        rows[r][f] = mrow[f] + mrow[F_ + f];
    }
    __syncthreads();
    for (int i = tid; i < K_ * F_; i += 256) {
        int k = i / F_, f = i % F_;
        rows[QT_ + k][f] = psum[k][f] / (float)counts[k];
    }
    __syncthreads();

    // B) projection: thread d = tid owns output column d; float2 LDS reads
    {
        const int d = tid;
        float wreg[F_];
#pragma unroll
        for (int f = 0; f < F_; ++f) wreg[f] = Wm[f * D_ + d];   // coalesced
        const float bd = bias[d];
        for (int r = 0; r < QT_ + K_; ++r) {
            const float2* row2 = (const float2*)rows[r];
            float acc = bd;
#pragma unroll
            for (int f2 = 0; f2 < F_ / 2; ++f2) {
                float2 rv = row2[f2];                            // ds_read_b64 broadcast
                acc += rv.x * wreg[2 * f2] + rv.y * wreg[2 * f2 + 1];
            }
            zbuf[r][d] = acc;
        }
    }
    __syncthreads();

    // C) distances: 25 (q,k) pairs striped over 4 waves
    const int wave = tid >> 6, lane = tid & 63;
    for (int p = wave; p < QT_ * K_; p += 4) {
        const int q = p / K_, k = p % K_;
        float s = 0.f;
#pragma unroll
        for (int j = 0; j < 4; ++j) {
            int d = lane + j * 64;
            float diff = zbuf[q][d] - zbuf[QT_ + k][d];
            s += diff * diff;
        }
        for (int off = 32; off > 0; off >>= 1) s += __shfl_down(s, off);
        if (lane == 0) out[(size_t)(b * NQ_ + q0 + q) * K_ + k] = -sqrtf(s);
    }
}

extern "C" void kernel_launch(void* const* d_in, const int* in_sizes, int n_in,
                              void* d_out, int out_size, void* d_ws, size_t ws_size,
                              hipStream_t stream) {
    const float* sx   = (const float*)d_in[0];   // support_x [32,50,128,64]
    const int*   sy   = (const int*)  d_in[1];   // support_y [32,50]
    const float* qx   = (const float*)d_in[2];   // query_x   [32,75,128,64]
    const float* Wm   = (const float*)d_in[3];   // W [64,256]
    const float* bias = (const float*)d_in[4];   // b [256]
    float* out = (float*)d_out;                  // [2400, 5]
    float* meanbuf = (float*)d_ws;               // B*125*128 floats = 2.0 MB

    meanpool_kernel<<<(B_ * NR_ * 2) / 4, 256, 0, stream>>>(sx, qx, meanbuf);
    proto_kernel<<<B_ * NTILE_, 256, 0, stream>>>(meanbuf, sy, Wm, bias, out);
}

// Round 7
// 174.305 us; speedup vs baseline: 1.0589x; 1.0589x over previous
//
#include <hip/hip_runtime.h>
#include <math.h>

#define B_  32
#define NS_ 50
#define NQ_ 75
#define T_  128
#define F_  64
#define D_  256
#define K_  5
#define NR_ (NS_ + NQ_)   // 125 items per episode (supports then queries)
#define QT_ 5             // query tile per stage-2 block (75 = 15 * 5)
#define NTILE_ 15

typedef float v4f __attribute__((ext_vector_type(4)));

// ---------------------------------------------------------------------------
// Stage 1: time-mean pool, ONE WAVE PER ITEM. No barriers, no LDS.
// Lane reads 32 float4 (each instr: wave reads 1 KB contiguous).
// R7: load burst restructured 32-deep -> 8-deep (8 temps + 2 accumulators,
// ~60 live VGPRs) so all 4000 waves are co-resident (32 waves/CU) in ONE
// dispatch round. (R4's 32-deep burst needed ~160 VGPR -> 12 waves/CU ->
// 1.3 rounds, second round latency-exposed. R6's launch_bounds cap of the
// same structure crashed the backend — restructure, don't cap.)
// ---------------------------------------------------------------------------
__global__ __launch_bounds__(256) void meanpool_kernel(
    const float* __restrict__ sx, const float* __restrict__ qx,
    float* __restrict__ meanbuf)
{
    const int wave = threadIdx.x >> 6, lane = threadIdx.x & 63;
    const int item = blockIdx.x * 4 + wave;        // 0 .. B*NR-1
    const int b = item / NR_, n = item % NR_;
    const float* src = (n < NS_)
        ? (sx + (size_t)(b * NS_ + n) * (T_ * F_))
        : (qx + (size_t)(b * NQ_ + (n - NS_)) * (T_ * F_));
    const v4f* src4 = (const v4f*)src;

    v4f a0 = 0.f, a1 = 0.f;
#pragma unroll
    for (int s = 0; s < 32; s += 8) {
        v4f v0 = __builtin_nontemporal_load(&src4[(s + 0) * 64 + lane]);
        v4f v1 = __builtin_nontemporal_load(&src4[(s + 1) * 64 + lane]);
        v4f v2 = __builtin_nontemporal_load(&src4[(s + 2) * 64 + lane]);
        v4f v3 = __builtin_nontemporal_load(&src4[(s + 3) * 64 + lane]);
        v4f v4 = __builtin_nontemporal_load(&src4[(s + 4) * 64 + lane]);
        v4f v5 = __builtin_nontemporal_load(&src4[(s + 5) * 64 + lane]);
        v4f v6 = __builtin_nontemporal_load(&src4[(s + 6) * 64 + lane]);
        v4f v7 = __builtin_nontemporal_load(&src4[(s + 7) * 64 + lane]);
        a0 += (v0 + v2) + (v4 + v6);
        a1 += (v1 + v3) + (v5 + v7);
    }
    v4f a = a0 + a1;

    // lanes {l, l+16, l+32, l+48} hold partials of the same f4-column
    a.x += __shfl_down(a.x, 32); a.y += __shfl_down(a.y, 32);
    a.z += __shfl_down(a.z, 32); a.w += __shfl_down(a.w, 32);
    a.x += __shfl_down(a.x, 16); a.y += __shfl_down(a.y, 16);
    a.z += __shfl_down(a.z, 16); a.w += __shfl_down(a.w, 16);

    if (lane < 16)
        ((v4f*)meanbuf)[(size_t)item * 16 + lane] = a * (1.f / T_);
}

// ---------------------------------------------------------------------------
// Stage 2: one block per (episode, query-tile of 5). 480 blocks, 256 threads.
// (Unchanged from R4 — known good.)
// ---------------------------------------------------------------------------
__global__ __launch_bounds__(256) void proto_kernel(
    const float* __restrict__ meanbuf, const int* __restrict__ sy,
    const float* __restrict__ Wm, const float* __restrict__ bias,
    float* __restrict__ out)
{
    __shared__ float rows[QT_ + K_][F_];   // [0..4] query means, [5..9] protomeans
    __shared__ float zbuf[QT_ + K_][D_];   // projected rows
    __shared__ int   labels[NS_];
    __shared__ float psum[K_][F_];
    __shared__ int   counts[K_];

    const int tid = threadIdx.x;
    const int bid = blockIdx.x;            // 0 .. B*NTILE-1
    const int b = bid / NTILE_, qt = bid % NTILE_;
    const int q0 = qt * QT_;

    if (tid < NS_) labels[tid] = sy[b * NS_ + tid];
    __syncthreads();

    // A) class sums over support means (threads 0..63, f = tid)
    if (tid < F_) {
        const int f = tid;
        float p0 = 0.f, p1 = 0.f, p2 = 0.f, p3 = 0.f, p4 = 0.f;
        for (int s = 0; s < NS_; ++s) {
            float v = meanbuf[((size_t)b * NR_ + s) * F_ + f];
            int l = labels[s];
            if      (l == 0) p0 += v;
            else if (l == 1) p1 += v;
            else if (l == 2) p2 += v;
            else if (l == 3) p3 += v;
            else             p4 += v;
        }
        psum[0][f] = p0; psum[1][f] = p1; psum[2][f] = p2;
        psum[3][f] = p3; psum[4][f] = p4;
    }
    if (tid < K_) {
        int c = 0;
        for (int s = 0; s < NS_; ++s) c += (labels[s] == tid);
        counts[tid] = c;
    }
    for (int i = tid; i < QT_ * F_; i += 256) {
        int r = i / F_, f = i % F_;
        rows[r][f] = meanbuf[((size_t)b * NR_ + NS_ + q0 + r) * F_ + f];
    }
    __syncthreads();
    for (int i = tid; i < K_ * F_; i += 256) {
        int k = i / F_, f = i % F_;
        rows[QT_ + k][f] = psum[k][f] / (float)counts[k];
    }
    __syncthreads();

    // B) projection: thread d = tid owns output column d; float2 LDS reads
    {
        const int d = tid;
        float wreg[F_];
#pragma unroll
        for (int f = 0; f < F_; ++f) wreg[f] = Wm[f * D_ + d];   // coalesced
        const float bd = bias[d];
        for (int r = 0; r < QT_ + K_; ++r) {
            const float2* row2 = (const float2*)rows[r];
            float acc = bd;
#pragma unroll
            for (int f2 = 0; f2 < F_ / 2; ++f2) {
                float2 rv = row2[f2];                            // ds_read_b64 broadcast
                acc += rv.x * wreg[2 * f2] + rv.y * wreg[2 * f2 + 1];
            }
            zbuf[r][d] = acc;
        }
    }
    __syncthreads();

    // C) distances: 25 (q,k) pairs striped over 4 waves
    const int wave = tid >> 6, lane = tid & 63;
    for (int p = wave; p < QT_ * K_; p += 4) {
        const int q = p / K_, k = p % K_;
        float s = 0.f;
#pragma unroll
        for (int j = 0; j < 4; ++j) {
            int d = lane + j * 64;
            float diff = zbuf[q][d] - zbuf[QT_ + k][d];
            s += diff * diff;
        }
        for (int off = 32; off > 0; off >>= 1) s += __shfl_down(s, off);
        if (lane == 0) out[(size_t)(b * NQ_ + q0 + q) * K_ + k] = -sqrtf(s);
    }
}

extern "C" void kernel_launch(void* const* d_in, const int* in_sizes, int n_in,
                              void* d_out, int out_size, void* d_ws, size_t ws_size,
                              hipStream_t stream) {
    const float* sx   = (const float*)d_in[0];   // support_x [32,50,128,64]
    const int*   sy   = (const int*)  d_in[1];   // support_y [32,50]
    const float* qx   = (const float*)d_in[2];   // query_x   [32,75,128,64]
    const float* Wm   = (const float*)d_in[3];   // W [64,256]
    const float* bias = (const float*)d_in[4];   // b [256]
    float* out = (float*)d_out;                  // [2400, 5]
    float* meanbuf = (float*)d_ws;               // B*125*64 floats = 1.0 MB

    meanpool_kernel<<<(B_ * NR_) / 4, 256, 0, stream>>>(sx, qx, meanbuf);
    proto_kernel<<<B_ * NTILE_, 256, 0, stream>>>(meanbuf, sy, Wm, bias, out);
}